// Round 13
// baseline (46.255 us; speedup 1.0000x reference)
//
#include <hip/hip_runtime.h>

#define IN_CH 3
#define OUT_CH 32
#define IN_FEAT 27
#define NB 5
#define NG 8
#define HH 256
#define WW 256
#define NPIX (16 * HH * WW)

// Phi record: 24 fp16 (18 real + 6 zero), 48 B, 16B-aligned in LDS
#define RECE 24
#define RECP 24
#define TW 66                            // halo tile width (64 + 2)
#define TROWS 10                         // halo rows (8 + 2)
#define NREC (TROWS * TW)                // 660 records per block
// K-packed B: 7 ksteps x 2 N-tiles x 64 lanes x 8 halves
#define NKS 7
#define WB2_HALVES (NKS * 2 * 64 * 8)    // 7168 halves = 14336 B
#define WS_NEEDED ((size_t)WB2_HALVES * 2 + 16)
// store-transpose scratch: per wave 32 ch x 36 dwords (32 px + 4 pad)
#define SCR_STRIDE 36
#define SCR_WAVE (32 * SCR_STRIDE)       // 1152 dwords = 4608 B

typedef __attribute__((ext_vector_type(8))) _Float16 half8;
typedef __attribute__((ext_vector_type(4))) float f32x4;

// Reference-exact phi (Cox-de Boor) -- fallback only
__device__ inline void kan_phi6(float xx, const float* g, const float* r1, const float* r2,
                                float* o6) {
    const float sig = 1.0f / (1.0f + __expf(-xx));
    o6[0] = xx * sig;
    float b0[7];
#pragma unroll
    for (int j = 0; j < 7; ++j) b0[j] = (xx >= g[j] && xx < g[j + 1]) ? 1.0f : 0.0f;
    float b1[6];
#pragma unroll
    for (int j = 0; j < 6; ++j)
        b1[j] = (xx - g[j]) * r1[j] * b0[j] + (g[j + 2] - xx) * r1[j + 1] * b0[j + 1];
#pragma unroll
    for (int j = 0; j < NB; ++j)
        o6[1 + j] = (xx - g[j]) * r2[j] * b1[j] + (g[j + 3] - xx) * r2[j + 1] * b1[j + 1];
}

__device__ inline void load_grid(const float* __restrict__ grid, float* g, float* r1, float* r2) {
#pragma unroll
    for (int j = 0; j < NG; ++j) g[j] = grid[j];
#pragma unroll
    for (int j = 0; j < NG - 1; ++j) r1[j] = 1.0f / (g[j + 1] - g[j]);
#pragma unroll
    for (int j = 0; j < NG - 2; ++j) r2[j] = 1.0f / (g[j + 2] - g[j]);
}

// ---------------------------------------------------------------------------
// Prep: weights -> K-packed B-fragment layout (fp16), as in R10/R11.
// ---------------------------------------------------------------------------
__global__ void kan_prepW(const float* __restrict__ bw, const float* __restrict__ sw,
                          const float* __restrict__ ss, const float* __restrict__ grid,
                          _Float16* __restrict__ wb) {
    int t = blockIdx.x * 256 + threadIdx.x;
    if (t >= NKS * 2 * 64) return;

    if (t == 0) {
        float* gt = (float*)(wb + WB2_HALVES);
        gt[0] = grid[0];
        gt[1] = 7.0f / (grid[7] - grid[0]);   // 1/h
    }

    const int lane = t & 63;
    const int nt = (t >> 6) & 1;
    const int kstep = t >> 7;
    const int o = nt * 16 + (lane & 15);
    const int kbase = kstep * 32 + (lane >> 4) * 8;
    half8 v8 = {0, 0, 0, 0, 0, 0, 0, 0};
#pragma unroll
    for (int e = 0; e < 8; ++e) {
        int k = kbase + e;
        float v = 0.0f;
        if (k < 216) {
            int tap = k / 24, within = k % 24;
            if (within < 18) {
                int c = within / 6, j = within % 6;
                int f = c * 9 + tap;
                int of = o * IN_FEAT + f;
                v = (j == 0) ? bw[of] : sw[of * NB + (j - 1)] * ss[of];
            }
        }
        v8[e] = (_Float16)v;
    }
    *(half8*)(wb + (size_t)t * 8) = v8;
}

// ---------------------------------------------------------------------------
// Fused kernel: block = 512 thr = 8 waves; tile = 64 wide x 8 rows.
//  Phase 1: 660 halo records (10x66) -> LDS, closed-form uniform B-spline
//           (redundancy 1.29x vs 1.55x at 4-row tiles).
//  Phase 2: wave wid owns row h0+wid: 4 M-tiles x 7 ksteps x 2 N -> 56 MFMA,
//           wave-private LDS transpose -> 4 x 1KB stores (full 128B lines).
// LDS 68.5 KB -> 2 blocks/CU, 16 waves/CU (same wave count as R11).
// ---------------------------------------------------------------------------
__global__ __launch_bounds__(512, 4) void kan_fused(const float* __restrict__ x,
                                                    const _Float16* __restrict__ wb,
                                                    float* __restrict__ out) {
    __shared__ _Float16 lPhi[NREC * RECP];       // 31680 B
    __shared__ float lScr[8 * SCR_WAVE];         // 36864 B

    const int tid = threadIdx.x;
    const int bid = blockIdx.x;
    const int strip = bid & 3;                   // 4 strips of 64 px
    const int rowg = (bid >> 2) & 31;            // 32 row-groups of 8
    const int b = bid >> 7;                      // 16 batches
    const int h0 = rowg * 8;
    const int w0 = strip * 64;

    const int lane = tid & 63;
    const int wid = tid >> 6;                    // 0..7
    const int r = lane & 15;      // A row (pixel) / B col (channel) within tile
    const int gq = lane >> 4;     // k-quarter (0..3)

    const float* gt = (const float*)(wb + WB2_HALVES);
    const float g0 = gt[0];
    const float invh = gt[1];

    // ---- Phase 1: phi halo tile (closed-form uniform quadratic B-spline) ----
    for (int ri = tid; ri < NREC; ri += 512) {
        const int dyR = ri / TW;             // 0..9
        const int wxR = ri - dyR * TW - 1;   // -1..64
        const int hy = h0 + dyR - 1;
        const int wx = w0 + wxR;
        const bool vld = ((unsigned)hy < HH) & ((unsigned)wx < WW);

        _Float16 rec[RECE];
#pragma unroll
        for (int c = 0; c < IN_CH; ++c) {
            const float xx = vld ? x[((b * IN_CH + c) << 16) + (hy << 8) + wx] : 0.0f;
            const float sig = 1.0f / (1.0f + __expf(-xx));
            rec[c * 6] = (_Float16)(xx * sig);
            const float u = (xx - g0) * invh;
            const float fi = floorf(u);
            const int i0 = (int)fi;
            const float t = u - fi;
            const float om = 1.0f - t;
            float wA = 0.5f * om * om;          // slot i0-2
            float wC = 0.5f * t * t;            // slot i0
            float wB = 1.0f - wA - wC;          // slot i0-1
            const bool valid = (fi >= 0.0f) & (i0 <= 6);
            wA = valid ? wA : 0.0f;
            wB = valid ? wB : 0.0f;
            wC = valid ? wC : 0.0f;
#pragma unroll
            for (int j = 0; j < NB; ++j) {
                float v = (j == i0 - 2) ? wA : ((j == i0 - 1) ? wB : ((j == i0) ? wC : 0.0f));
                rec[c * 6 + 1 + j] = (_Float16)v;
            }
        }
#pragma unroll
        for (int j = 18; j < RECE; ++j) rec[j] = (_Float16)0.0f;

        half8* dst = (half8*)(lPhi + ri * RECP);
        dst[0] = *(half8*)(rec + 0);
        dst[1] = *(half8*)(rec + 8);
        dst[2] = *(half8*)(rec + 16);
    }
    __syncthreads();

    // ---- B-fragments: from global (L2-resident) AFTER the barrier ----
    half8 bf[NKS * 2];
#pragma unroll
    for (int i = 0; i < NKS * 2; ++i)
        bf[i] = *(const half8*)(wb + ((size_t)(i * 64 + lane)) * 8);

    // per-kstep chunk decode: q = kstep*4 + gq -> tap = q/3, part = q%3
    int rowoff[NKS], partoff[NKS];
    bool kvalid[NKS];
#pragma unroll
    for (int k = 0; k < NKS; ++k) {
        const int q = k * 4 + gq;
        const int tap = q / 3;
        const int part = q - tap * 3;
        kvalid[k] = (q < 27);
        const int dyk = tap / 3;
        const int dxk = tap - dyk * 3;
        rowoff[k] = (kvalid[k] ? dyk : 0) * TW + (kvalid[k] ? dxk : 0);
        partoff[k] = part * 8;
    }

    // ---- Phase 2: one row per wave; 2 halves x {2 M-tiles}, transpose ----
    const int hrow = h0 + wid;
    float* lT = lScr + wid * SCR_WAVE;
    const int chl = lane >> 3;            // 0..7
    const int pxl = (lane & 7) * 4;       // 0..28
    const int rowbase = wid * TW;

#pragma unroll
    for (int h = 0; h < 2; ++h) {
        f32x4 accA0 = {0.f, 0.f, 0.f, 0.f}, accA1 = {0.f, 0.f, 0.f, 0.f};
        f32x4 accB0 = {0.f, 0.f, 0.f, 0.f}, accB1 = {0.f, 0.f, 0.f, 0.f};
#pragma unroll
        for (int mm = 0; mm < 2; ++mm) {
            const int m = h * 2 + mm;
#pragma unroll
            for (int k = 0; k < NKS; ++k) {
                half8 v = {0, 0, 0, 0, 0, 0, 0, 0};
                if (kvalid[k]) {
                    const int ridx = rowbase + rowoff[k] + m * 16 + r;
                    v = *(const half8*)(lPhi + ridx * RECP + partoff[k]);
                }
                if (mm == 0) {
                    accA0 = __builtin_amdgcn_mfma_f32_16x16x32_f16(v, bf[k * 2 + 0], accA0, 0, 0, 0);
                    accA1 = __builtin_amdgcn_mfma_f32_16x16x32_f16(v, bf[k * 2 + 1], accA1, 0, 0, 0);
                } else {
                    accB0 = __builtin_amdgcn_mfma_f32_16x16x32_f16(v, bf[k * 2 + 0], accB0, 0, 0, 0);
                    accB1 = __builtin_amdgcn_mfma_f32_16x16x32_f16(v, bf[k * 2 + 1], accB1, 0, 0, 0);
                }
            }
        }

        // wave-private transpose: ch-major scratch [32][36]
        *(f32x4*)(lT + r        * SCR_STRIDE + 0  + gq * 4) = accA0;
        *(f32x4*)(lT + (16 + r) * SCR_STRIDE + 0  + gq * 4) = accA1;
        *(f32x4*)(lT + r        * SCR_STRIDE + 16 + gq * 4) = accB0;
        *(f32x4*)(lT + (16 + r) * SCR_STRIDE + 16 + gq * 4) = accB1;

        // readback + linear stores: instr j = 8 channels x full 128B lines
#pragma unroll
        for (int j = 0; j < 4; ++j) {
            const int ch = j * 8 + chl;
            f32x4 v = *(const f32x4*)(lT + ch * SCR_STRIDE + pxl);
            float* op = out + (((size_t)(b * OUT_CH + ch)) << 16) + (hrow << 8) + w0 + h * 32 + pxl;
            *(f32x4*)op = v;
        }
    }
}

// ===========================================================================
// Fallback (round-1 fp32 path) if ws_size is too small for wb
// ===========================================================================
__global__ void kan_combine_weights(const float* __restrict__ bw,
                                    const float* __restrict__ sw,
                                    const float* __restrict__ ss,
                                    float* __restrict__ wc) {
    int idx = blockIdx.x * blockDim.x + threadIdx.x;
    if (idx >= IN_FEAT * 6 * OUT_CH) return;
    int o = idx & 31;
    int j = (idx >> 5) % 6;
    int f = idx / (6 * 32);
    float v;
    if (j == 0) v = bw[o * IN_FEAT + f];
    else        v = sw[(o * IN_FEAT + f) * NB + (j - 1)] * ss[o * IN_FEAT + f];
    wc[idx] = v;
}

__global__ __launch_bounds__(256) void kan_main(const float* __restrict__ x,
                                                const float* __restrict__ grid,
                                                const float* __restrict__ wc,
                                                float* __restrict__ out) {
    const int p = blockIdx.x * blockDim.x + threadIdx.x;
    const int w = p & (WW - 1);
    const int h = (p >> 8) & (HH - 1);
    const int b = p >> 16;
    float g[NG], r1[NG - 1], r2[NG - 2];
    load_grid(grid, g, r1, r2);
    float acc[OUT_CH];
#pragma unroll
    for (int o = 0; o < OUT_CH; ++o) acc[o] = 0.0f;
    const float* xb = x + b * (IN_CH * HH * WW);
    for (int c = 0; c < IN_CH; ++c) {
        const float* xc = xb + c * (HH * WW);
#pragma unroll
        for (int dy = 0; dy < 3; ++dy) {
            const int hy = h + dy - 1;
            const bool vy = (hy >= 0) && (hy < HH);
#pragma unroll
            for (int dx = 0; dx < 3; ++dx) {
                const int wx = w + dx - 1;
                const bool vld = vy && (wx >= 0) && (wx < WW);
                const float xx = vld ? xc[hy * WW + wx] : 0.0f;
                float o6[6];
                kan_phi6(xx, g, r1, r2, o6);
                const float* wf = wc + (c * 9 + dy * 3 + dx) * (6 * OUT_CH);
#pragma unroll
                for (int jj = 0; jj < 6; ++jj) {
                    const float* wj = wf + jj * OUT_CH;
#pragma unroll
                    for (int o = 0; o < OUT_CH; ++o) acc[o] += o6[jj] * wj[o];
                }
            }
        }
    }
    float* ob = out + (size_t)b * (OUT_CH * HH * WW) + h * WW + w;
#pragma unroll
    for (int o = 0; o < OUT_CH; ++o) ob[o * (HH * WW)] = acc[o];
}

// ===========================================================================
extern "C" void kernel_launch(void* const* d_in, const int* in_sizes, int n_in,
                              void* d_out, int out_size, void* d_ws, size_t ws_size,
                              hipStream_t stream) {
    const float* x    = (const float*)d_in[0];
    const float* bw   = (const float*)d_in[1];
    const float* sw   = (const float*)d_in[2];
    const float* ss   = (const float*)d_in[3];
    const float* grid = (const float*)d_in[4];
    float* out = (float*)d_out;

    if (ws_size >= WS_NEEDED) {
        _Float16* wb = (_Float16*)d_ws;
        kan_prepW<<<4, 256, 0, stream>>>(bw, sw, ss, grid, wb);
        kan_fused<<<NPIX / 512, 512, 0, stream>>>(x, wb, out);   // 2048 blocks
    } else {
        float* wc = (float*)d_ws;
        kan_combine_weights<<<(IN_FEAT * 6 * OUT_CH + 255) / 256, 256, 0, stream>>>(bw, sw, ss, wc);
        kan_main<<<NPIX / 256, 256, 0, stream>>>(x, grid, wc, out);
    }
}

// Round 15
// 42.782 us; speedup vs baseline: 1.0812x; 1.0812x over previous
//
#include <hip/hip_runtime.h>

#define IN_CH 3
#define OUT_CH 32
#define IN_FEAT 27
#define NB 5
#define NG 8
#define HH 256
#define WW 256
#define NPIX (16 * HH * WW)

// Phi record: 24 fp16 (18 real + 6 zero), 48 B, 16B-aligned in LDS
#define RECE 24
#define RECP 24
#define TW 66                            // halo tile width (64 + 2)
#define TROWS 6                          // halo rows (4 + 2)
#define NREC (TROWS * TW)                // 396 records per block
// K-packed B: 7 ksteps x 2 N-tiles x 64 lanes x 8 halves
#define NKS 7
#define WB2_HALVES (NKS * 2 * 64 * 8)    // 7168 halves = 14336 B
#define WS_NEEDED ((size_t)WB2_HALVES * 2 + 16)
// store-transpose scratch: per wave 32 ch x 36 dwords (32 px + 4 pad)
#define SCR_STRIDE 36
#define SCR_WAVE (32 * SCR_STRIDE)       // 1152 dwords = 4608 B

typedef __attribute__((ext_vector_type(8))) _Float16 half8;
typedef __attribute__((ext_vector_type(4))) float f32x4;

// Reference-exact phi (Cox-de Boor) -- fallback only
__device__ inline void kan_phi6(float xx, const float* g, const float* r1, const float* r2,
                                float* o6) {
    const float sig = 1.0f / (1.0f + __expf(-xx));
    o6[0] = xx * sig;
    float b0[7];
#pragma unroll
    for (int j = 0; j < 7; ++j) b0[j] = (xx >= g[j] && xx < g[j + 1]) ? 1.0f : 0.0f;
    float b1[6];
#pragma unroll
    for (int j = 0; j < 6; ++j)
        b1[j] = (xx - g[j]) * r1[j] * b0[j] + (g[j + 2] - xx) * r1[j + 1] * b0[j + 1];
#pragma unroll
    for (int j = 0; j < NB; ++j)
        o6[1 + j] = (xx - g[j]) * r2[j] * b1[j] + (g[j + 3] - xx) * r2[j + 1] * b1[j + 1];
}

__device__ inline void load_grid(const float* __restrict__ grid, float* g, float* r1, float* r2) {
#pragma unroll
    for (int j = 0; j < NG; ++j) g[j] = grid[j];
#pragma unroll
    for (int j = 0; j < NG - 1; ++j) r1[j] = 1.0f / (g[j + 1] - g[j]);
#pragma unroll
    for (int j = 0; j < NG - 2; ++j) r2[j] = 1.0f / (g[j + 2] - g[j]);
}

// ---------------------------------------------------------------------------
// Prep: weights -> K-packed B-fragment layout (fp16), as in R10/R11.
// ---------------------------------------------------------------------------
__global__ void kan_prepW(const float* __restrict__ bw, const float* __restrict__ sw,
                          const float* __restrict__ ss, const float* __restrict__ grid,
                          _Float16* __restrict__ wb) {
    int t = blockIdx.x * 256 + threadIdx.x;
    if (t >= NKS * 2 * 64) return;

    if (t == 0) {
        float* gt = (float*)(wb + WB2_HALVES);
        gt[0] = grid[0];
        gt[1] = 7.0f / (grid[7] - grid[0]);   // 1/h
    }

    const int lane = t & 63;
    const int nt = (t >> 6) & 1;
    const int kstep = t >> 7;
    const int o = nt * 16 + (lane & 15);
    const int kbase = kstep * 32 + (lane >> 4) * 8;
    half8 v8 = {0, 0, 0, 0, 0, 0, 0, 0};
#pragma unroll
    for (int e = 0; e < 8; ++e) {
        int k = kbase + e;
        float v = 0.0f;
        if (k < 216) {
            int tap = k / 24, within = k % 24;
            if (within < 18) {
                int c = within / 6, j = within % 6;
                int f = c * 9 + tap;
                int of = o * IN_FEAT + f;
                v = (j == 0) ? bw[of] : sw[of * NB + (j - 1)] * ss[of];
            }
        }
        v8[e] = (_Float16)v;
    }
    *(half8*)(wb + (size_t)t * 8) = v8;
}

// ---------------------------------------------------------------------------
// Fused kernel (R11 + corrected XCD swizzle): block = 256 thr; 64 x 4 tile.
// Grid 4096 = 8 XCD x 512: bid = (orig&7)*512 + orig>>3 (bijective) ->
// each XCD owns 512 contiguous tiles = 2 full batch-images.
// ---------------------------------------------------------------------------
__global__ __launch_bounds__(256, 4) void kan_fused(const float* __restrict__ x,
                                                    const _Float16* __restrict__ wb,
                                                    float* __restrict__ out) {
    __shared__ _Float16 lPhi[NREC * RECP];       // 19008 B
    __shared__ float lScr[4 * SCR_WAVE];         // 18432 B

    const int tid = threadIdx.x;
    const int orig = blockIdx.x;
    const int bid = (orig & 7) * 512 + (orig >> 3);   // bijective: 4096 = 8*512
    const int strip = bid & 3;
    const int rowg = (bid >> 2) & 63;
    const int b = bid >> 8;
    const int h0 = rowg * 4;
    const int w0 = strip * 64;

    const int lane = tid & 63;
    const int wid = tid >> 6;
    const int r = lane & 15;      // A row (pixel) / B col (channel) within tile
    const int gq = lane >> 4;     // k-quarter (0..3)

    const float* gt = (const float*)(wb + WB2_HALVES);
    const float g0 = gt[0];
    const float invh = gt[1];

    // ---- Phase 1: phi halo tile (closed-form uniform quadratic B-spline) ----
    for (int ri = tid; ri < NREC; ri += 256) {
        const int dyR = ri / TW;             // 0..5
        const int wxR = ri - dyR * TW - 1;   // -1..64
        const int hy = h0 + dyR - 1;
        const int wx = w0 + wxR;
        const bool vld = ((unsigned)hy < HH) & ((unsigned)wx < WW);

        _Float16 rec[RECE];
#pragma unroll
        for (int c = 0; c < IN_CH; ++c) {
            const float xx = vld ? x[((b * IN_CH + c) << 16) + (hy << 8) + wx] : 0.0f;
            const float sig = 1.0f / (1.0f + __expf(-xx));
            rec[c * 6] = (_Float16)(xx * sig);
            const float u = (xx - g0) * invh;
            const float fi = floorf(u);
            const int i0 = (int)fi;
            const float t = u - fi;
            const float om = 1.0f - t;
            float wA = 0.5f * om * om;          // slot i0-2
            float wC = 0.5f * t * t;            // slot i0
            float wB = 1.0f - wA - wC;          // slot i0-1
            const bool valid = (fi >= 0.0f) & (i0 <= 6);
            wA = valid ? wA : 0.0f;
            wB = valid ? wB : 0.0f;
            wC = valid ? wC : 0.0f;
#pragma unroll
            for (int j = 0; j < NB; ++j) {
                float v = (j == i0 - 2) ? wA : ((j == i0 - 1) ? wB : ((j == i0) ? wC : 0.0f));
                rec[c * 6 + 1 + j] = (_Float16)v;
            }
        }
#pragma unroll
        for (int j = 18; j < RECE; ++j) rec[j] = (_Float16)0.0f;

        half8* dst = (half8*)(lPhi + ri * RECP);
        dst[0] = *(half8*)(rec + 0);
        dst[1] = *(half8*)(rec + 8);
        dst[2] = *(half8*)(rec + 16);
    }
    __syncthreads();

    // ---- B-fragments: from global (L2-resident) AFTER the barrier ----
    half8 bf[NKS * 2];
#pragma unroll
    for (int i = 0; i < NKS * 2; ++i)
        bf[i] = *(const half8*)(wb + ((size_t)(i * 64 + lane)) * 8);

    // per-kstep chunk decode: q = kstep*4 + gq -> tap = q/3, part = q%3
    int rowoff[NKS], partoff[NKS];
    bool kvalid[NKS];
#pragma unroll
    for (int k = 0; k < NKS; ++k) {
        const int q = k * 4 + gq;
        const int tap = q / 3;
        const int part = q - tap * 3;
        kvalid[k] = (q < 27);
        const int dyk = tap / 3;
        const int dxk = tap - dyk * 3;
        rowoff[k] = (wid + (kvalid[k] ? dyk : 0)) * TW + (kvalid[k] ? dxk : 0);
        partoff[k] = part * 8;
    }

    // ---- Phase 2: 2 halves x {2 M-tiles, MFMA}, transpose, linear stores ----
    const int hrow = h0 + wid;
    float* lT = lScr + wid * SCR_WAVE;
    const int chl = lane >> 3;            // 0..7
    const int pxl = (lane & 7) * 4;       // 0..28

#pragma unroll
    for (int h = 0; h < 2; ++h) {
        f32x4 accA0 = {0.f, 0.f, 0.f, 0.f}, accA1 = {0.f, 0.f, 0.f, 0.f};
        f32x4 accB0 = {0.f, 0.f, 0.f, 0.f}, accB1 = {0.f, 0.f, 0.f, 0.f};
#pragma unroll
        for (int mm = 0; mm < 2; ++mm) {
            const int m = h * 2 + mm;
#pragma unroll
            for (int k = 0; k < NKS; ++k) {
                half8 v = {0, 0, 0, 0, 0, 0, 0, 0};
                if (kvalid[k]) {
                    const int ridx = rowoff[k] + m * 16 + r;
                    v = *(const half8*)(lPhi + ridx * RECP + partoff[k]);
                }
                if (mm == 0) {
                    accA0 = __builtin_amdgcn_mfma_f32_16x16x32_f16(v, bf[k * 2 + 0], accA0, 0, 0, 0);
                    accA1 = __builtin_amdgcn_mfma_f32_16x16x32_f16(v, bf[k * 2 + 1], accA1, 0, 0, 0);
                } else {
                    accB0 = __builtin_amdgcn_mfma_f32_16x16x32_f16(v, bf[k * 2 + 0], accB0, 0, 0, 0);
                    accB1 = __builtin_amdgcn_mfma_f32_16x16x32_f16(v, bf[k * 2 + 1], accB1, 0, 0, 0);
                }
            }
        }

        // wave-private transpose: ch-major scratch [32][36]
        *(f32x4*)(lT + r        * SCR_STRIDE + 0  + gq * 4) = accA0;
        *(f32x4*)(lT + (16 + r) * SCR_STRIDE + 0  + gq * 4) = accA1;
        *(f32x4*)(lT + r        * SCR_STRIDE + 16 + gq * 4) = accB0;
        *(f32x4*)(lT + (16 + r) * SCR_STRIDE + 16 + gq * 4) = accB1;

        // readback + linear stores: instr j = 8 channels x full 128B lines
#pragma unroll
        for (int j = 0; j < 4; ++j) {
            const int ch = j * 8 + chl;
            f32x4 v = *(const f32x4*)(lT + ch * SCR_STRIDE + pxl);
            float* op = out + (((size_t)(b * OUT_CH + ch)) << 16) + (hrow << 8) + w0 + h * 32 + pxl;
            *(f32x4*)op = v;
        }
    }
}

// ===========================================================================
// Fallback (round-1 fp32 path) if ws_size is too small for wb
// ===========================================================================
__global__ void kan_combine_weights(const float* __restrict__ bw,
                                    const float* __restrict__ sw,
                                    const float* __restrict__ ss,
                                    float* __restrict__ wc) {
    int idx = blockIdx.x * blockDim.x + threadIdx.x;
    if (idx >= IN_FEAT * 6 * OUT_CH) return;
    int o = idx & 31;
    int j = (idx >> 5) % 6;
    int f = idx / (6 * 32);
    float v;
    if (j == 0) v = bw[o * IN_FEAT + f];
    else        v = sw[(o * IN_FEAT + f) * NB + (j - 1)] * ss[o * IN_FEAT + f];
    wc[idx] = v;
}

__global__ __launch_bounds__(256) void kan_main(const float* __restrict__ x,
                                                const float* __restrict__ grid,
                                                const float* __restrict__ wc,
                                                float* __restrict__ out) {
    const int p = blockIdx.x * blockDim.x + threadIdx.x;
    const int w = p & (WW - 1);
    const int h = (p >> 8) & (HH - 1);
    const int b = p >> 16;
    float g[NG], r1[NG - 1], r2[NG - 2];
    load_grid(grid, g, r1, r2);
    float acc[OUT_CH];
#pragma unroll
    for (int o = 0; o < OUT_CH; ++o) acc[o] = 0.0f;
    const float* xb = x + b * (IN_CH * HH * WW);
    for (int c = 0; c < IN_CH; ++c) {
        const float* xc = xb + c * (HH * WW);
#pragma unroll
        for (int dy = 0; dy < 3; ++dy) {
            const int hy = h + dy - 1;
            const bool vy = (hy >= 0) && (hy < HH);
#pragma unroll
            for (int dx = 0; dx < 3; ++dx) {
                const int wx = w + dx - 1;
                const bool vld = vy && (wx >= 0) && (wx < WW);
                const float xx = vld ? xc[hy * WW + wx] : 0.0f;
                float o6[6];
                kan_phi6(xx, g, r1, r2, o6);
                const float* wf = wc + (c * 9 + dy * 3 + dx) * (6 * OUT_CH);
#pragma unroll
                for (int jj = 0; jj < 6; ++jj) {
                    const float* wj = wf + jj * OUT_CH;
#pragma unroll
                    for (int o = 0; o < OUT_CH; ++o) acc[o] += o6[jj] * wj[o];
                }
            }
        }
    }
    float* ob = out + (size_t)b * (OUT_CH * HH * WW) + h * WW + w;
#pragma unroll
    for (int o = 0; o < OUT_CH; ++o) ob[o * (HH * WW)] = acc[o];
}

// ===========================================================================
extern "C" void kernel_launch(void* const* d_in, const int* in_sizes, int n_in,
                              void* d_out, int out_size, void* d_ws, size_t ws_size,
                              hipStream_t stream) {
    const float* x    = (const float*)d_in[0];
    const float* bw   = (const float*)d_in[1];
    const float* sw   = (const float*)d_in[2];
    const float* ss   = (const float*)d_in[3];
    const float* grid = (const float*)d_in[4];
    float* out = (float*)d_out;

    if (ws_size >= WS_NEEDED) {
        _Float16* wb = (_Float16*)d_ws;
        kan_prepW<<<4, 256, 0, stream>>>(bw, sw, ss, grid, wb);
        kan_fused<<<NPIX / 256, 256, 0, stream>>>(x, wb, out);   // 4096 blocks
    } else {
        float* wc = (float*)d_ws;
        kan_combine_weights<<<(IN_FEAT * 6 * OUT_CH + 255) / 256, 256, 0, stream>>>(bw, sw, ss, wc);
        kan_main<<<NPIX / 256, 256, 0, stream>>>(x, grid, wc, out);
    }
}